// Round 3
// baseline (96.608 us; speedup 1.0000x reference)
//
#include <hip/hip_runtime.h>
#include <math.h>

// Problem constants
#define B_ 16
#define NL_ 12
#define L1_ 197
#define D_ 768
#define E_ 4
#define K_ 3
#define C_ 21
#define IMG_ 224
#define LP_ 196    // L1 - 1 patch tokens
#define LT_ 14     // l-rows per expert tile; 196 = 14*14 exactly (no tail)
#define NLT_ 14
#define RS4_ 193   // LDS row stride in float4 (192+1 -> rows cycle bank groups)

// ---------------------------------------------------------------------------
// Kernel 0 (prep): blocks [0,84): transpose expert_W [E][D][C] -> eWt [E][C][D]
//                  blocks [84,276): gate_score[b,nl,:] (one wave per (b,nl))
// ---------------------------------------------------------------------------
__global__ __launch_bounds__(256) void prep_kernel(
        const float* __restrict__ feat,
        const float* __restrict__ gW,
        const float* __restrict__ gb,
        const float* __restrict__ eW,
        float* __restrict__ eWt,
        float* __restrict__ gs) {
    int blk = blockIdx.x;
    int t = threadIdx.x;
    if (blk < E_ * C_) {                     // transpose part
        int e = blk / C_, c = blk % C_;
        for (int d = t; d < D_; d += 256)
            eWt[((size_t)e * C_ + c) * D_ + d] = eW[((size_t)e * D_ + d) * C_ + c];
    } else {                                 // gate part (lane 0..63 active)
        int bl = blk - E_ * C_;              // b*NL + nl
        if (t < 64) {
            const float* cls = feat + (size_t)bl * L1_ * D_;
            float a0 = 0.f, a1 = 0.f, a2 = 0.f, a3 = 0.f;
            for (int q = 0; q < D_ / 64; ++q) {
                int d = t + 64 * q;
                float x = cls[d];
                float4 w = *(const float4*)(gW + (size_t)d * E_);
                a0 += x * w.x; a1 += x * w.y; a2 += x * w.z; a3 += x * w.w;
            }
            for (int off = 32; off > 0; off >>= 1) {
                a0 += __shfl_down(a0, off);
                a1 += __shfl_down(a1, off);
                a2 += __shfl_down(a2, off);
                a3 += __shfl_down(a3, off);
            }
            if (t == 0) {
                gs[bl * E_ + 0] = a0 + gb[0];
                gs[bl * E_ + 1] = a1 + gb[1];
                gs[bl * E_ + 2] = a2 + gb[2];
                gs[bl * E_ + 3] = a3 + gb[3];
            }
        }
    }
}

// ---------------------------------------------------------------------------
// Kernel 1 (expert): block = (b, l-tile of 14, e). 896 blocks, 256 threads.
// Inline per-(b,e) selection (softmax over 12 layers -> top3 -> softmax),
// stage mixed rows in padded LDS, then 98 compute threads: (l = t%14,
// c0 = t/14), each owning 3 c's {c0, c0+7, c0+14}: one LDS b128 read feeds
// 3 W rows and 12 independent accumulator chains. Writes per-expert
// partials (with bias, pre-scaled by 0.25) for the upsampler to reduce.
// ---------------------------------------------------------------------------
__global__ __launch_bounds__(256) void expert_kernel(
        const float* __restrict__ feat,
        const float* __restrict__ eWt,
        const float* __restrict__ eb,
        const float* __restrict__ gs,
        float* __restrict__ part) {
    int blk = blockIdx.x;             // (b*NLT + lt)*E + e
    int e = blk & 3;
    int r = blk >> 2;
    int b = r / NLT_;
    int l0 = (r % NLT_) * LT_;
    int t = threadIdx.x;

    // ---- inline selection (block-uniform; every thread computes it) ----
    float p[NL_];
    float mx = -1e30f;
    #pragma unroll
    for (int nl = 0; nl < NL_; ++nl) {
        float v = gs[(b * NL_ + nl) * E_ + e];
        p[nl] = v; mx = fmaxf(mx, v);
    }
    float ssum = 0.f;
    #pragma unroll
    for (int nl = 0; nl < NL_; ++nl) { p[nl] = expf(p[nl] - mx); ssum += p[nl]; }
    float inv = 1.0f / ssum;
    #pragma unroll
    for (int nl = 0; nl < NL_; ++nl) p[nl] *= inv;
    int idx0 = 0, idx1 = 0, idx2 = 0;
    float v0, v1, v2;
    {
        unsigned used = 0;
        float best = -1.f; int bi = 0;
        #pragma unroll
        for (int nl = 0; nl < NL_; ++nl) if (p[nl] > best) { best = p[nl]; bi = nl; }
        idx0 = bi; v0 = best; used = 1u << bi;
        best = -1.f; bi = 0;
        #pragma unroll
        for (int nl = 0; nl < NL_; ++nl)
            if (!((used >> nl) & 1u) && p[nl] > best) { best = p[nl]; bi = nl; }
        idx1 = bi; v1 = best; used |= 1u << bi;
        best = -1.f; bi = 0;
        #pragma unroll
        for (int nl = 0; nl < NL_; ++nl)
            if (!((used >> nl) & 1u) && p[nl] > best) { best = p[nl]; bi = nl; }
        idx2 = bi; v2 = best;
    }
    float x1 = expf(v1 - v0), x2 = expf(v2 - v0);
    float isw = 1.0f / (1.0f + x1 + x2);
    float w0 = isw, w1 = x1 * isw, w2 = x2 * isw;

    // ---- stage mixed rows (14 contiguous token rows per source) ----
    __shared__ __align__(16) float4 smix[LT_ * RS4_];   // ~43.2 KiB
    const float4* feat4 = (const float4*)feat;
    const float4* f0 = feat4 + ((size_t)(b * NL_ + idx0) * L1_ + 1 + l0) * (D_ / 4);
    const float4* f1 = feat4 + ((size_t)(b * NL_ + idx1) * L1_ + 1 + l0) * (D_ / 4);
    const float4* f2 = feat4 + ((size_t)(b * NL_ + idx2) * L1_ + 1 + l0) * (D_ / 4);
    for (int i = t; i < LT_ * (D_ / 4); i += 256) {
        int rr = i / (D_ / 4);
        int d4 = i - rr * (D_ / 4);
        float4 a = f0[i], bb = f1[i], cc = f2[i];
        float4 m;
        m.x = w0 * a.x + w1 * bb.x + w2 * cc.x;
        m.y = w0 * a.y + w1 * bb.y + w2 * cc.y;
        m.z = w0 * a.z + w1 * bb.z + w2 * cc.z;
        m.w = w0 * a.w + w1 * bb.w + w2 * cc.w;
        smix[rr * RS4_ + d4] = m;
    }
    __syncthreads();

    // ---- compute: 98 threads, 3 c's each ----
    if (t < LT_ * 7) {
        int l = t % LT_;
        int c0 = t / LT_;                 // 0..6
        const float4* mrow = smix + l * RS4_;
        const float4* W0 = (const float4*)eWt + (size_t)(e * C_ + c0) * (D_ / 4);
        const float4* W1 = W0 + 7 * (D_ / 4);
        const float4* W2 = W0 + 14 * (D_ / 4);
        float4 a0 = {0, 0, 0, 0}, a1 = {0, 0, 0, 0}, a2 = {0, 0, 0, 0};
        #pragma unroll 4
        for (int d4 = 0; d4 < D_ / 4; ++d4) {
            float4 m = mrow[d4];
            float4 x = W0[d4], y = W1[d4], z = W2[d4];
            a0.x += m.x * x.x; a0.y += m.y * x.y; a0.z += m.z * x.z; a0.w += m.w * x.w;
            a1.x += m.x * y.x; a1.y += m.y * y.y; a1.z += m.z * y.z; a1.w += m.w * y.w;
            a2.x += m.x * z.x; a2.y += m.y * z.y; a2.z += m.z * z.z; a2.w += m.w * z.w;
        }
        float s0 = (a0.x + a0.y) + (a0.z + a0.w);
        float s1 = (a1.x + a1.y) + (a1.z + a1.w);
        float s2 = (a2.x + a2.y) + (a2.z + a2.w);
        size_t pb = ((size_t)b * C_ + c0) * E_ + e;
        part[pb * LP_ + l0 + l]                  = 0.25f * (s0 + eb[e * C_ + c0]);
        part[(pb + 7 * E_) * LP_ + l0 + l]       = 0.25f * (s1 + eb[e * C_ + c0 + 7]);
        part[(pb + 14 * E_) * LP_ + l0 + l]      = 0.25f * (s2 + eb[e * C_ + c0 + 14]);
    }
}

// ---------------------------------------------------------------------------
// Kernel 2: reduce 4 expert partials + bilinear upsample 14x14 -> 224x224.
// Block per (b, c, row-quarter). Write-BW bound.
// ---------------------------------------------------------------------------
__global__ __launch_bounds__(256) void upsample_kernel(
        const float* __restrict__ part, float* __restrict__ out) {
    int bq = blockIdx.x;
    int q = bq & 3;           // quarter: 56 output rows
    int bc = bq >> 2;         // b*C + c
    int t = threadIdx.x;
    __shared__ float s[LP_];
    if (t < LP_) {
        const float* pp = part + (size_t)bc * E_ * LP_ + t;
        s[t] = (pp[0] + pp[LP_]) + (pp[2 * LP_] + pp[3 * LP_]);
    }
    __syncthreads();
    float4* out4 = (float4*)out + (size_t)bc * IMG_ * (IMG_ / 4);
    for (int i = t; i < 56 * 56; i += 256) {
        int oy = q * 56 + i / 56;
        int ox4 = (i % 56) * 4;
        float fy = (oy + 0.5f) * 0.0625f - 0.5f;
        fy = fminf(fmaxf(fy, 0.0f), 13.0f);
        int y0 = (int)fy;
        float ty = fy - (float)y0;
        int y1 = min(y0 + 1, 13);
        const float* r0 = s + y0 * 14;
        const float* r1 = s + y1 * 14;
        float4 res;
        float* rp = (float*)&res;
        for (int u = 0; u < 4; ++u) {
            int ox = ox4 + u;
            float fx = (ox + 0.5f) * 0.0625f - 0.5f;
            fx = fminf(fmaxf(fx, 0.0f), 13.0f);
            int x0 = (int)fx;
            float tx = fx - (float)x0;
            int x1 = min(x0 + 1, 13);
            float v00 = r0[x0], v01 = r0[x1];
            float v10 = r1[x0], v11 = r1[x1];
            float top = v00 + tx * (v01 - v00);
            float bot = v10 + tx * (v11 - v10);
            rp[u] = top + ty * (bot - top);
        }
        out4[oy * 56 + (i % 56)] = res;
    }
}

// ---------------------------------------------------------------------------
extern "C" void kernel_launch(void* const* d_in, const int* in_sizes, int n_in,
                              void* d_out, int out_size, void* d_ws, size_t ws_size,
                              hipStream_t stream) {
    const float* feat = (const float*)d_in[0];   // (B, NL, 197, 768)
    const float* gW   = (const float*)d_in[1];   // (768, 4)
    const float* gb   = (const float*)d_in[2];   // (4,)
    const float* eW   = (const float*)d_in[3];   // (4, 768, 21)
    const float* eb   = (const float*)d_in[4];   // (4, 21)
    float* out = (float*)d_out;                  // (16, 21, 224, 224)

    float* ws   = (float*)d_ws;
    float* gs   = ws;                              // B*NL*E          = 768
    float* eWt  = ws + 768;                        // E*C*D           = 64512
    float* part = ws + 768 + 64512;                // B*C*E*LP        = 263424

    hipLaunchKernelGGL(prep_kernel, dim3(E_ * C_ + B_ * NL_), dim3(256), 0, stream,
                       feat, gW, gb, eW, eWt, gs);
    hipLaunchKernelGGL(expert_kernel, dim3(B_ * NLT_ * E_), dim3(256), 0, stream,
                       feat, eWt, eb, gs, part);
    hipLaunchKernelGGL(upsample_kernel, dim3(B_ * C_ * 4), dim3(256), 0, stream,
                       part, out);
}

// Round 4
// 52.857 us; speedup vs baseline: 1.8277x; 1.8277x over previous
//
#include <hip/hip_runtime.h>
#include <math.h>

// Problem constants
#define B_ 16
#define NL_ 12
#define L1_ 197
#define D_ 768
#define E_ 4
#define K_ 3
#define C_ 21
#define IMG_ 224
#define LP_ 196
#define NJ_ 84      // real output cols (E*C)
#define MT_ 52      // m-rows per gemm block (52,52,52,40)
#define KSTEPS 24   // 768 / 32

typedef __attribute__((ext_vector_type(8))) short short8;
typedef __attribute__((ext_vector_type(4))) float f32x4;
typedef unsigned short ushort_t;

__device__ __forceinline__ ushort_t bf16rne(float x) {
    unsigned u = __float_as_uint(x);
    unsigned r = (u + 0x7FFFu + ((u >> 16) & 1u)) >> 16;
    return (ushort_t)r;
}

// per-(b,e) gating: softmax over 12 layers -> top3 (ties: lowest idx) -> softmax
__device__ __forceinline__ void select_be(const float* __restrict__ gs, int b, int e,
                                          int idx[3], float w[3]) {
    float p[NL_]; float mx = -1e30f;
    #pragma unroll
    for (int nl = 0; nl < NL_; ++nl) { float v = gs[(b * NL_ + nl) * E_ + e]; p[nl] = v; mx = fmaxf(mx, v); }
    float ss = 0.f;
    #pragma unroll
    for (int nl = 0; nl < NL_; ++nl) { p[nl] = expf(p[nl] - mx); ss += p[nl]; }
    float inv = 1.0f / ss;
    #pragma unroll
    for (int nl = 0; nl < NL_; ++nl) p[nl] *= inv;
    unsigned used = 0; float v[3];
    #pragma unroll
    for (int k = 0; k < 3; ++k) {
        float best = -1.f; int bi = 0;
        #pragma unroll
        for (int nl = 0; nl < NL_; ++nl)
            if (!((used >> nl) & 1u) && p[nl] > best) { best = p[nl]; bi = nl; }
        used |= 1u << bi; idx[k] = bi; v[k] = best;
    }
    float x1 = expf(v[1] - v[0]), x2 = expf(v[2] - v[0]);
    float isw = 1.0f / (1.0f + x1 + x2);
    w[0] = isw; w[1] = x1 * isw; w[2] = x2 * isw;
}

// ---------------------------------------------------------------------------
// Kernel 0 (prep): blocks [0,192): gate scores (one wave per (b,nl))
//                  blocks [192,288): WtB[j][k] = bf16(expert_W[e][k][c]), j=21e+c
// ---------------------------------------------------------------------------
__global__ __launch_bounds__(256) void prep_kernel(
        const float* __restrict__ feat, const float* __restrict__ gW,
        const float* __restrict__ gb, const float* __restrict__ eW,
        ushort_t* __restrict__ WtB, float* __restrict__ gs) {
    int blk = blockIdx.x, t = threadIdx.x;
    if (blk < B_ * NL_) {
        if (t < 64) {
            const float* cls = feat + (size_t)blk * L1_ * D_;
            float a0 = 0.f, a1 = 0.f, a2 = 0.f, a3 = 0.f;
            for (int q = 0; q < D_ / 64; ++q) {
                int d = t + 64 * q;
                float x = cls[d];
                float4 w = *(const float4*)(gW + (size_t)d * E_);
                a0 += x * w.x; a1 += x * w.y; a2 += x * w.z; a3 += x * w.w;
            }
            for (int off = 32; off > 0; off >>= 1) {
                a0 += __shfl_down(a0, off); a1 += __shfl_down(a1, off);
                a2 += __shfl_down(a2, off); a3 += __shfl_down(a3, off);
            }
            if (t == 0) {
                gs[blk * E_ + 0] = a0 + gb[0]; gs[blk * E_ + 1] = a1 + gb[1];
                gs[blk * E_ + 2] = a2 + gb[2]; gs[blk * E_ + 3] = a3 + gb[3];
            }
        }
    } else {
        int j = blk - B_ * NL_;                 // 0..95
        if (j < NJ_) {
            int e = j / C_, c = j % C_;
            for (int k = t; k < D_; k += 256)
                WtB[(size_t)j * D_ + k] = bf16rne(eW[((size_t)e * D_ + k) * C_ + c]);
        } else {
            for (int k = t; k < D_; k += 256) WtB[(size_t)j * D_ + k] = 0;
        }
    }
}

// ---------------------------------------------------------------------------
// Kernel 1 (select): 1 block. t<64: per-(b,e) top3+weights -> topi/wgt.
// t<192: per-(b,nl) "is this layer selected by any expert" flag.
// ---------------------------------------------------------------------------
__global__ __launch_bounds__(256) void select_kernel(
        const float* __restrict__ gs, int* __restrict__ topi,
        float* __restrict__ wgt, int* __restrict__ flag) {
    __shared__ int sidx[B_ * E_ * 3];
    int t = threadIdx.x;
    if (t < B_ * E_) {
        int b = t >> 2, e = t & 3;
        int idx[3]; float w[3];
        select_be(gs, b, e, idx, w);
        #pragma unroll
        for (int k = 0; k < 3; ++k) {
            topi[t * 3 + k] = idx[k]; wgt[t * 3 + k] = w[k]; sidx[t * 3 + k] = idx[k];
        }
    }
    __syncthreads();
    if (t < B_ * NL_) {
        int b = t / NL_, nl = t % NL_;
        int f = 0;
        #pragma unroll
        for (int ek = 0; ek < 12; ++ek) f |= (sidx[b * 12 + ek] == nl);
        flag[t] = f;
    }
}

// ---------------------------------------------------------------------------
// Kernel 2 (GEMM): proj[b,nl,j,l] = feat[b,nl,1+l,:] . Wall[:,j]  (bf16 MFMA)
// Block = (b*NL+nl, m-tile of 52 rows); skipped if layer unselected.
// 4 waves; wave w owns rows [w*16, w*16+16) x all 96 cols (6 n-tiles).
// LDS double-buffered A(64x32) / B(96x32) bf16 chunks, rows padded to 80B,
// 16B-slot XOR-swizzled by (row&3) -> <=2-way banks.
// ---------------------------------------------------------------------------
__global__ __launch_bounds__(256, 3) void gemm_kernel(
        const float* __restrict__ feat, const ushort_t* __restrict__ WtB,
        const int* __restrict__ flag, float* __restrict__ proj) {
    int blk = blockIdx.x;
    int tile = blk & 3;
    int bn = blk >> 2;                  // b*NL + nl
    if (flag[bn] == 0) return;
    int rows_real = min(MT_, LP_ - tile * MT_);   // 52,52,52,40

    __shared__ short8 Ab[2][64 * 5];    // row*5 + slot, slot in [0,4), 80B rows
    __shared__ short8 Bb[2][96 * 5];

    int t = threadIdx.x;
    int w = t >> 6, lane = t & 63;
    int r = t >> 2, kg = t & 3;         // staging coords: row r, 8-elem k-group kg
    int aslotw = kg ^ (r & 3);
    bool avalid = r < rows_real;
    bool bvalid1 = t < 128;             // second B chunk (j = 64 + r)

    const float* arow_base = feat + ((size_t)bn * L1_ + 1 + tile * MT_ + r) * D_;
    const ushort_t* brow0 = WtB + (size_t)r * D_;
    const ushort_t* brow1 = WtB + (size_t)(64 + r) * D_;

    // LDS read indices (per compute lane)
    int arow = w * 16 + (lane & 15);
    int aidx = arow * 5 + ((lane >> 4) ^ (arow & 3));
    int bidx[6];
    #pragma unroll
    for (int nt = 0; nt < 6; ++nt) {
        int jr = nt * 16 + (lane & 15);
        bidx[nt] = jr * 5 + ((lane >> 4) ^ (jr & 3));
    }

    // ---- prologue: stage step 0 ----
    {
        f32x4 fa0 = {0,0,0,0}, fa1 = {0,0,0,0};
        if (avalid) { const f32x4* p = (const f32x4*)(arow_base); fa0 = p[kg*2]; fa1 = p[kg*2+1]; }
        short8 av;
        #pragma unroll
        for (int i = 0; i < 4; ++i) { av[i] = (short)bf16rne(fa0[i]); av[i+4] = (short)bf16rne(fa1[i]); }
        Ab[0][r * 5 + aslotw] = av;
        Bb[0][r * 5 + aslotw] = *(const short8*)(brow0 + kg * 8);
        if (bvalid1) Bb[0][(64 + r) * 5 + aslotw] = *(const short8*)(brow1 + kg * 8);
    }
    __syncthreads();

    f32x4 acc[6];
    #pragma unroll
    for (int nt = 0; nt < 6; ++nt) acc[nt] = (f32x4)0.0f;

    for (int s = 0; s < KSTEPS; ++s) {
        int cur = s & 1;
        // issue next-step global loads
        f32x4 fa0 = {0,0,0,0}, fa1 = {0,0,0,0};
        short8 wb0, wb1;
        if (s + 1 < KSTEPS) {
            int k0 = (s + 1) * 32;
            if (avalid) { const f32x4* p = (const f32x4*)(arow_base + k0); fa0 = p[kg*2]; fa1 = p[kg*2+1]; }
            wb0 = *(const short8*)(brow0 + k0 + kg * 8);
            if (bvalid1) wb1 = *(const short8*)(brow1 + k0 + kg * 8);
        }
        // compute current buffer
        short8 af = Ab[cur][aidx];
        #pragma unroll
        for (int nt = 0; nt < 6; ++nt)
            acc[nt] = __builtin_amdgcn_mfma_f32_16x16x32_bf16(af, Bb[cur][bidx[nt]], acc[nt], 0, 0, 0);
        // write next buffer
        if (s + 1 < KSTEPS) {
            int nb = cur ^ 1;
            short8 av;
            #pragma unroll
            for (int i = 0; i < 4; ++i) { av[i] = (short)bf16rne(fa0[i]); av[i+4] = (short)bf16rne(fa1[i]); }
            Ab[nb][r * 5 + aslotw] = av;
            Bb[nb][r * 5 + aslotw] = wb0;
            if (bvalid1) Bb[nb][(64 + r) * 5 + aslotw] = wb1;
        }
        __syncthreads();
    }

    // ---- epilogue: D frag: col = lane&15, rows = (lane>>4)*4 + i ----
    int lr = w * 16 + ((lane >> 4) << 2);
    int l0 = tile * MT_ + lr;
    if (lr < MT_ && l0 < LP_) {
        #pragma unroll
        for (int nt = 0; nt < 6; ++nt) {
            int j = nt * 16 + (lane & 15);
            if (j < NJ_)
                *(f32x4*)(proj + ((size_t)bn * NJ_ + j) * LP_ + l0) = acc[nt];
        }
    }
}

// ---------------------------------------------------------------------------
// Kernel 3: mix (gather selected proj rows, weight, expert-mean, bias)
//           + bilinear upsample 14x14 -> 224x224. Block per (b, c, quarter).
// ---------------------------------------------------------------------------
__global__ __launch_bounds__(256) void upsample_kernel(
        const float* __restrict__ proj, const int* __restrict__ topi,
        const float* __restrict__ wgt, const float* __restrict__ eb,
        float* __restrict__ out) {
    int bq = blockIdx.x;
    int q = bq & 3;
    int bc = bq >> 2;          // b*C + c
    int b = bc / C_, c = bc % C_;
    int t = threadIdx.x;
    __shared__ float s[LP_];
    if (t < LP_) {
        float a = 0.25f * (eb[c] + eb[C_ + c] + eb[2 * C_ + c] + eb[3 * C_ + c]);
        #pragma unroll
        for (int e = 0; e < E_; ++e) {
            int base = (b * E_ + e) * 3;
            #pragma unroll
            for (int k = 0; k < 3; ++k) {
                int nl = topi[base + k];
                float wv = 0.25f * wgt[base + k];
                a += wv * proj[(((size_t)b * NL_ + nl) * NJ_ + e * C_ + c) * LP_ + t];
            }
        }
        s[t] = a;
    }
    __syncthreads();
    float4* out4 = (float4*)out + (size_t)bc * IMG_ * (IMG_ / 4);
    for (int i = t; i < 56 * 56; i += 256) {
        int oy = q * 56 + i / 56;
        int ox4 = (i % 56) * 4;
        float fy = (oy + 0.5f) * 0.0625f - 0.5f;
        fy = fminf(fmaxf(fy, 0.0f), 13.0f);
        int y0 = (int)fy;
        float ty = fy - (float)y0;
        int y1 = min(y0 + 1, 13);
        const float* r0 = s + y0 * 14;
        const float* r1 = s + y1 * 14;
        float4 res;
        float* rp = (float*)&res;
        for (int u = 0; u < 4; ++u) {
            int ox = ox4 + u;
            float fx = (ox + 0.5f) * 0.0625f - 0.5f;
            fx = fminf(fmaxf(fx, 0.0f), 13.0f);
            int x0 = (int)fx;
            float tx = fx - (float)x0;
            int x1 = min(x0 + 1, 13);
            float v00 = r0[x0], v01 = r0[x1];
            float v10 = r1[x0], v11 = r1[x1];
            float top = v00 + tx * (v01 - v00);
            float bot = v10 + tx * (v11 - v10);
            rp[u] = top + ty * (bot - top);
        }
        out4[oy * 56 + (i % 56)] = res;
    }
}

// ---------------------------------------------------------------------------
extern "C" void kernel_launch(void* const* d_in, const int* in_sizes, int n_in,
                              void* d_out, int out_size, void* d_ws, size_t ws_size,
                              hipStream_t stream) {
    const float* feat = (const float*)d_in[0];   // (16, 12, 197, 768)
    const float* gW   = (const float*)d_in[1];   // (768, 4)
    const float* gb   = (const float*)d_in[2];   // (4,)
    const float* eW   = (const float*)d_in[3];   // (4, 768, 21)
    const float* eb   = (const float*)d_in[4];   // (4, 21)
    float* out = (float*)d_out;                  // (16, 21, 224, 224)

    float* ws = (float*)d_ws;
    float*    gs   = ws;                         // 768 f           [0,768)
    int*      topi = (int*)(ws + 768);           // 192             [768,960)
    float*    wgt  = ws + 960;                   // 192             [960,1152)
    int*      flag = (int*)(ws + 1152);          // 192             [1152,1344)
    ushort_t* WtB  = (ushort_t*)(ws + 1536);     // 96*768 bf16     [1536,38400)
    float*    proj = ws + 38400;                 // 16*12*84*196 f  (~12.6 MB)

    hipLaunchKernelGGL(prep_kernel, dim3(B_ * NL_ + 96), dim3(256), 0, stream,
                       feat, gW, gb, eW, WtB, gs);
    hipLaunchKernelGGL(select_kernel, dim3(1), dim3(256), 0, stream,
                       gs, topi, wgt, flag);
    hipLaunchKernelGGL(gemm_kernel, dim3(B_ * NL_ * 4), dim3(256), 0, stream,
                       feat, WtB, flag, proj);
    hipLaunchKernelGGL(upsample_kernel, dim3(B_ * C_ * 4), dim3(256), 0, stream,
                       proj, topi, wgt, eb, out);
}